// Round 1
// baseline (2032.923 us; speedup 1.0000x reference)
//
#include <hip/hip_runtime.h>
#include <cmath>

#define T_TOK 4096
#define DM    512
#define DFF   2048
#define NE    16
#define PP    128

// ---------------------------------------------------------------------------
// Generic tiled SGEMM: C[M,N] = A[M,K] * B[N,K]^T + bias[N]
// BM=BN=64, BK=16, 256 threads, 4x4 per thread. Requires M%64==0, N%64==0, K%16==0.
// ---------------------------------------------------------------------------
__global__ __launch_bounds__(256) void sgemm_nt_bias(
    const float* __restrict__ A, const float* __restrict__ B,
    const float* __restrict__ bias, float* __restrict__ C,
    int M, int N, int K)
{
  __shared__ __align__(16) float As[16][68];
  __shared__ __align__(16) float Bs[16][68];
  const int bm = blockIdx.x * 64;
  const int bn = blockIdx.y * 64;
  const int tid = threadIdx.x;
  const int tx = tid & 15;    // 0..15 -> cols tx*4..+4
  const int ty = tid >> 4;    // 0..15 -> rows ty*4..+4

  float acc[4][4] = {{0.f}};

  for (int k0 = 0; k0 < K; k0 += 16) {
    // load A tile 64x16 (one float4 along K per thread)
    {
      int r  = tid >> 2;            // 0..63
      int c4 = (tid & 3) * 4;       // 0,4,8,12
      float4 v = *(const float4*)(A + (size_t)(bm + r) * K + k0 + c4);
      As[c4+0][r] = v.x; As[c4+1][r] = v.y; As[c4+2][r] = v.z; As[c4+3][r] = v.w;
    }
    // load B tile 64x16 (B is [N,K] row-major; we use B^T)
    {
      int r  = tid >> 2;
      int c4 = (tid & 3) * 4;
      float4 v = *(const float4*)(B + (size_t)(bn + r) * K + k0 + c4);
      Bs[c4+0][r] = v.x; Bs[c4+1][r] = v.y; Bs[c4+2][r] = v.z; Bs[c4+3][r] = v.w;
    }
    __syncthreads();
    #pragma unroll
    for (int k = 0; k < 16; ++k) {
      float4 a4 = *(const float4*)&As[k][ty*4];
      float4 b4 = *(const float4*)&Bs[k][tx*4];
      float a[4] = {a4.x, a4.y, a4.z, a4.w};
      float b[4] = {b4.x, b4.y, b4.z, b4.w};
      #pragma unroll
      for (int i = 0; i < 4; ++i)
        #pragma unroll
        for (int j = 0; j < 4; ++j)
          acc[i][j] += a[i] * b[j];
    }
    __syncthreads();
  }
  #pragma unroll
  for (int i = 0; i < 4; ++i) {
    int row = bm + ty*4 + i;
    #pragma unroll
    for (int j = 0; j < 4; ++j) {
      int col = bn + tx*4 + j;
      C[(size_t)row * N + col] = acc[i][j] + bias[col];
    }
  }
}

// ---------------------------------------------------------------------------
// GRU elementwise: gates gx,gh [T,3P] in (r,z,n) order -> h [T,P]
// ---------------------------------------------------------------------------
__global__ void gru_elem(const float* __restrict__ gx, const float* __restrict__ gh,
                         const float* __restrict__ hprev, float* __restrict__ hout)
{
  int i = blockIdx.x * blockDim.x + threadIdx.x;   // i < T*P
  int t = i >> 7, p = i & 127;
  const float* gxr = gx + (size_t)t * 384;
  const float* ghr = gh + (size_t)t * 384;
  float xr = gxr[p], xz = gxr[128 + p], xn = gxr[256 + p];
  float hr = ghr[p], hz = ghr[128 + p], hn = ghr[256 + p];
  float r = 1.f / (1.f + expf(-(xr + hr)));
  float z = 1.f / (1.f + expf(-(xz + hz)));
  float n = tanhf(xn + r * hn);
  hout[i] = (1.f - z) * n + z * hprev[i];
}

// ---------------------------------------------------------------------------
// Router: per token, logits = h.Wr^T + br ; softmax ; top-2 (stable); renorm;
// append (token,slot) to per-expert lists. One wave per token.
// ---------------------------------------------------------------------------
__global__ void router_topk(const float* __restrict__ h, const float* __restrict__ Wr,
                            const float* __restrict__ br,
                            float* __restrict__ wgt, int* __restrict__ tokslot,
                            int* __restrict__ cnt)
{
  int wave = threadIdx.x >> 6;
  int lane = threadIdx.x & 63;
  int t = blockIdx.x * 4 + wave;

  float logit = 0.f;
  if (lane < NE) {
    const float* hr = h + (size_t)t * PP;
    const float* wr = Wr + (size_t)lane * PP;
    float s = 0.f;
    #pragma unroll 8
    for (int p = 0; p < PP; ++p) s += hr[p] * wr[p];
    logit = s + br[lane];
  }
  float l[NE];
  #pragma unroll
  for (int e = 0; e < NE; ++e) l[e] = __shfl(logit, e, 64);

  if (lane == 0) {
    float mx = l[0];
    #pragma unroll
    for (int e = 1; e < NE; ++e) mx = fmaxf(mx, l[e]);
    float p[NE];
    #pragma unroll
    for (int e = 0; e < NE; ++e) p[e] = expf(l[e] - mx);
    // top-2 on p (same order as softmax probs; normalization cancels in renorm)
    int i0 = 0; float m0 = p[0];
    #pragma unroll
    for (int e = 1; e < NE; ++e) { if (p[e] > m0) { m0 = p[e]; i0 = e; } }
    int i1 = -1; float m1 = -1.f;
    #pragma unroll
    for (int e = 0; e < NE; ++e) { if (e != i0 && p[e] > m1) { m1 = p[e]; i1 = e; } }
    float inv = 1.f / (m0 + m1);
    float w0 = m0 * inv, w1 = m1 * inv;
    int pos0 = atomicAdd(&cnt[i0], 1);
    tokslot[(size_t)i0 * T_TOK + pos0] = (t << 1);
    wgt[(size_t)i0 * T_TOK + pos0] = w0;
    int pos1 = atomicAdd(&cnt[i1], 1);
    tokslot[(size_t)i1 * T_TOK + pos1] = (t << 1) | 1;
    wgt[(size_t)i1 * T_TOK + pos1] = w1;
  }
}

// ---------------------------------------------------------------------------
// Expert FFN, gathered: per (expert e, tile of 64 tokens):
//   y = relu(xg @ W1[e] + b1[e]) @ W2[e] + b2[e];  part[slot][tok] = w * y
// ff streamed in chunks of 128; out accum 8 tokens x 16 cols = 128 regs/thread.
// ---------------------------------------------------------------------------
__global__ __launch_bounds__(256) void expert_ffn(
    const float* __restrict__ x,
    const float* __restrict__ W1, const float* __restrict__ b1,
    const float* __restrict__ W2, const float* __restrict__ b2,
    const int* __restrict__ cnt, const int* __restrict__ tokslot,
    const float* __restrict__ wgt,
    float* __restrict__ pA, float* __restrict__ pB)
{
  const int e = blockIdx.y;
  const int n = cnt[e];
  const int tstart = blockIdx.x * 64;
  if (tstart >= n) return;

  __shared__ int   ltok[64];
  __shared__ int   lslot[64];
  __shared__ float lw[64];
  __shared__ __align__(16) float xk[64][65];    // gathered x, K-chunk of 64
  __shared__ __align__(16) float ht[64][129];   // relu'd hidden chunk of 128

  const int tid = threadIdx.x;
  if (tid < 64) {
    int idx = tstart + tid;
    if (idx < n) {
      int ts = tokslot[(size_t)e * T_TOK + idx];
      ltok[tid]  = ts >> 1;
      lslot[tid] = ts & 1;
      lw[tid]    = wgt[(size_t)e * T_TOK + idx];
    } else { ltok[tid] = -1; lslot[tid] = 0; lw[tid] = 0.f; }
  }
  __syncthreads();

  const int tg = tid >> 5;   // 0..7 : token group (8 tokens each)
  const int fg = tid & 31;   // GEMM1: f cols fg*4..+4 ; GEMM2: d cols fg*16..+16

  const float* W1e = W1 + (size_t)e * DM * DFF;
  const float* W2e = W2 + (size_t)e * DFF * DM;

  float oacc[8][16];
  #pragma unroll
  for (int i = 0; i < 8; ++i)
    #pragma unroll
    for (int j = 0; j < 16; ++j) oacc[i][j] = 0.f;

  for (int fc = 0; fc < DFF; fc += 128) {
    float hacc[8][4] = {{0.f}};
    for (int dk = 0; dk < DM; dk += 64) {
      // load xk[64][64] (gathered rows, float4)
      #pragma unroll
      for (int l = 0; l < 4; ++l) {
        int idx = tid + l * 256;        // 0..1023 float4 slots
        int r   = idx >> 4;             // row 0..63
        int c4  = (idx & 15) * 4;       // col 0..60
        int trow = ltok[r]; if (trow < 0) trow = 0;
        float4 v = *(const float4*)(x + (size_t)trow * DM + dk + c4);
        xk[r][c4+0] = v.x; xk[r][c4+1] = v.y; xk[r][c4+2] = v.z; xk[r][c4+3] = v.w;
      }
      __syncthreads();
      #pragma unroll 4
      for (int d = 0; d < 64; ++d) {
        float4 w = *(const float4*)(W1e + (size_t)(dk + d) * DFF + fc + fg * 4);
        float xs[8];
        #pragma unroll
        for (int i = 0; i < 8; ++i) xs[i] = xk[tg*8 + i][d];
        #pragma unroll
        for (int i = 0; i < 8; ++i) {
          hacc[i][0] += xs[i] * w.x;
          hacc[i][1] += xs[i] * w.y;
          hacc[i][2] += xs[i] * w.z;
          hacc[i][3] += xs[i] * w.w;
        }
      }
      __syncthreads();
    }
    // bias + relu -> ht
    #pragma unroll
    for (int j = 0; j < 4; ++j) {
      float bv = b1[(size_t)e * DFF + fc + fg*4 + j];
      #pragma unroll
      for (int i = 0; i < 8; ++i) {
        float v = hacc[i][j] + bv;
        ht[tg*8 + i][fg*4 + j] = v > 0.f ? v : 0.f;
      }
    }
    __syncthreads();
    // GEMM2: oacc += ht[64][128] * W2e[fc..fc+128][:]
    #pragma unroll 2
    for (int f = 0; f < 128; ++f) {
      float hs[8];
      #pragma unroll
      for (int i = 0; i < 8; ++i) hs[i] = ht[tg*8 + i][f];
      const float* w2r = W2e + (size_t)(fc + f) * DM + fg * 16;
      float4 w0 = *(const float4*)(w2r + 0);
      float4 w1 = *(const float4*)(w2r + 4);
      float4 w2v = *(const float4*)(w2r + 8);
      float4 w3 = *(const float4*)(w2r + 12);
      #pragma unroll
      for (int i = 0; i < 8; ++i) {
        float hv = hs[i];
        oacc[i][0]  += hv * w0.x;  oacc[i][1]  += hv * w0.y;
        oacc[i][2]  += hv * w0.z;  oacc[i][3]  += hv * w0.w;
        oacc[i][4]  += hv * w1.x;  oacc[i][5]  += hv * w1.y;
        oacc[i][6]  += hv * w1.z;  oacc[i][7]  += hv * w1.w;
        oacc[i][8]  += hv * w2v.x; oacc[i][9]  += hv * w2v.y;
        oacc[i][10] += hv * w2v.z; oacc[i][11] += hv * w2v.w;
        oacc[i][12] += hv * w3.x;  oacc[i][13] += hv * w3.y;
        oacc[i][14] += hv * w3.z;  oacc[i][15] += hv * w3.w;
      }
    }
    __syncthreads();
  }

  // epilogue: (oacc + b2) * w -> part[slot][token]
  float bb[16];
  #pragma unroll
  for (int j = 0; j < 16; ++j) bb[j] = b2[(size_t)e * DM + fg*16 + j];
  #pragma unroll
  for (int i = 0; i < 8; ++i) {
    int r = tg*8 + i;
    int trow = ltok[r];
    if (trow < 0) continue;
    float w = lw[r];
    float* dst = (lslot[r] ? pB : pA) + (size_t)trow * DM + fg * 16;
    #pragma unroll
    for (int j = 0; j < 16; j += 4) {
      float4 o;
      o.x = (oacc[i][j+0] + bb[j+0]) * w;
      o.y = (oacc[i][j+1] + bb[j+1]) * w;
      o.z = (oacc[i][j+2] + bb[j+2]) * w;
      o.w = (oacc[i][j+3] + bb[j+3]) * w;
      *(float4*)(dst + j) = o;
    }
  }
}

__global__ void zero_cnt(int* cnt) { if (threadIdx.x < NE) cnt[threadIdx.x] = 0; }

__global__ void combine_out(const float4* __restrict__ pA, const float4* __restrict__ pB,
                            float4* __restrict__ out)
{
  int i = blockIdx.x * blockDim.x + threadIdx.x;   // i < T*DM/4
  float4 a = pA[i], b = pB[i];
  out[i] = make_float4(a.x + b.x, a.y + b.y, a.z + b.z, a.w + b.w);
}

// ---------------------------------------------------------------------------
extern "C" void kernel_launch(void* const* d_in, const int* in_sizes, int n_in,
                              void* d_out, int out_size, void* d_ws, size_t ws_size,
                              hipStream_t stream)
{
  const float* x      = (const float*)d_in[0];
  const float* h_prev = (const float*)d_in[1];
  const float* Wp     = (const float*)d_in[2];
  const float* bp     = (const float*)d_in[3];
  const float* W_ih   = (const float*)d_in[4];
  const float* W_hh   = (const float*)d_in[5];
  const float* b_ih   = (const float*)d_in[6];
  const float* b_hh   = (const float*)d_in[7];
  const float* Wr     = (const float*)d_in[8];
  const float* br     = (const float*)d_in[9];
  const float* W1     = (const float*)d_in[10];
  const float* b1     = (const float*)d_in[11];
  const float* W2     = (const float*)d_in[12];
  const float* b2     = (const float*)d_in[13];
  (void)in_sizes; (void)n_in; (void)out_size; (void)ws_size;

  float* out  = (float*)d_out;                       // [T, DM]
  float* hout = out + (size_t)T_TOK * DM;            // [T, PP]

  float* ws  = (float*)d_ws;
  float* xp  = ws;                                   // [T, PP]        524288
  float* reg = ws + (size_t)T_TOK * PP;              // shared region:
  float* gx  = reg;                                  // [T, 3P] 1572864
  float* gh  = reg + (size_t)T_TOK * 384;            // [T, 3P] 1572864
  float* pA  = reg;                                  // [T, DM] 2097152 (reuse, after GRU)
  float* pB  = reg + (size_t)T_TOK * DM;             // [T, DM] 2097152
  float* wgt = reg + (size_t)2 * T_TOK * DM;         // [E, T]  65536
  int*   cnt = (int*)(wgt + (size_t)NE * T_TOK);     // [E]
  int*   tokslot = cnt + 16;                         // [E, T]

  zero_cnt<<<1, 64, 0, stream>>>(cnt);

  // xp = x @ Wp^T + bp          [4096,128] = [4096,512][512,128]
  sgemm_nt_bias<<<dim3(T_TOK/64, PP/64), 256, 0, stream>>>(x, Wp, bp, xp, T_TOK, PP, DM);
  // gx = xp @ W_ih^T + b_ih     [4096,384] = [4096,128][128,384]
  sgemm_nt_bias<<<dim3(T_TOK/64, 384/64), 256, 0, stream>>>(xp, W_ih, b_ih, gx, T_TOK, 384, PP);
  // gh = h_prev @ W_hh^T + b_hh
  sgemm_nt_bias<<<dim3(T_TOK/64, 384/64), 256, 0, stream>>>(h_prev, W_hh, b_hh, gh, T_TOK, 384, PP);
  // GRU -> h (directly into d_out region 2)
  gru_elem<<<(T_TOK * PP) / 256, 256, 0, stream>>>(gx, gh, h_prev, hout);
  // router + top-2 + gather lists
  router_topk<<<T_TOK / 4, 256, 0, stream>>>(hout, Wr, br, wgt, tokslot, cnt);
  // expert FFN (gathered, top-2 only)
  expert_ffn<<<dim3(64, NE), 256, 0, stream>>>(x, W1, b1, W2, b2, cnt, tokslot, wgt, pA, pB);
  // out = pA + pB
  combine_out<<<(T_TOK * DM / 4) / 256, 256, 0, stream>>>((const float4*)pA, (const float4*)pB, (float4*)out);
}

// Round 2
// 501.541 us; speedup vs baseline: 4.0534x; 4.0534x over previous
//
#include <hip/hip_runtime.h>
#include <cmath>

#define T_TOK 4096
#define DM    512
#define DFF   2048
#define NE    16
#define PP    128

typedef __attribute__((ext_vector_type(8))) short bfrag;      // 8 bf16 (4 VGPRs)
typedef __attribute__((ext_vector_type(4))) float f32x4;
typedef __attribute__((ext_vector_type(8))) unsigned short us8;

__device__ __forceinline__ unsigned short f2bf(float f) {
  unsigned int u = __float_as_uint(f);
  unsigned int r = (u + 0x7FFFu + ((u >> 16) & 1u)) >> 16;
  return (unsigned short)r;
}

#define GLOAD_LDS16(g, l) __builtin_amdgcn_global_load_lds( \
    (const __attribute__((address_space(1))) void*)(g), \
    (__attribute__((address_space(3))) void*)(l), 16, 0, 0)

// ---------------------------------------------------------------------------
// f32 tiled SGEMM: C[M,N] = A[M,K] * B[N,K]^T + bias[N]   (routing chain, f32)
// ---------------------------------------------------------------------------
__global__ __launch_bounds__(256) void sgemm_nt_bias(
    const float* __restrict__ A, const float* __restrict__ B,
    const float* __restrict__ bias, float* __restrict__ C,
    int M, int N, int K)
{
  __shared__ __align__(16) float As[16][68];
  __shared__ __align__(16) float Bs[16][68];
  const int bm = blockIdx.x * 64;
  const int bn = blockIdx.y * 64;
  const int tid = threadIdx.x;
  const int tx = tid & 15;
  const int ty = tid >> 4;

  float acc[4][4] = {{0.f}};

  for (int k0 = 0; k0 < K; k0 += 16) {
    {
      int r  = tid >> 2;
      int c4 = (tid & 3) * 4;
      float4 v = *(const float4*)(A + (size_t)(bm + r) * K + k0 + c4);
      As[c4+0][r] = v.x; As[c4+1][r] = v.y; As[c4+2][r] = v.z; As[c4+3][r] = v.w;
    }
    {
      int r  = tid >> 2;
      int c4 = (tid & 3) * 4;
      float4 v = *(const float4*)(B + (size_t)(bn + r) * K + k0 + c4);
      Bs[c4+0][r] = v.x; Bs[c4+1][r] = v.y; Bs[c4+2][r] = v.z; Bs[c4+3][r] = v.w;
    }
    __syncthreads();
    #pragma unroll
    for (int k = 0; k < 16; ++k) {
      float4 a4 = *(const float4*)&As[k][ty*4];
      float4 b4 = *(const float4*)&Bs[k][tx*4];
      float a[4] = {a4.x, a4.y, a4.z, a4.w};
      float b[4] = {b4.x, b4.y, b4.z, b4.w};
      #pragma unroll
      for (int i = 0; i < 4; ++i)
        #pragma unroll
        for (int j = 0; j < 4; ++j)
          acc[i][j] += a[i] * b[j];
    }
    __syncthreads();
  }
  #pragma unroll
  for (int i = 0; i < 4; ++i) {
    int row = bm + ty*4 + i;
    #pragma unroll
    for (int j = 0; j < 4; ++j) {
      int col = bn + tx*4 + j;
      C[(size_t)row * N + col] = acc[i][j] + bias[col];
    }
  }
}

// ---------------------------------------------------------------------------
// GRU elementwise
// ---------------------------------------------------------------------------
__global__ void gru_elem(const float* __restrict__ gx, const float* __restrict__ gh,
                         const float* __restrict__ hprev, float* __restrict__ hout)
{
  int i = blockIdx.x * blockDim.x + threadIdx.x;
  int t = i >> 7, p = i & 127;
  const float* gxr = gx + (size_t)t * 384;
  const float* ghr = gh + (size_t)t * 384;
  float xr = gxr[p], xz = gxr[128 + p], xn = gxr[256 + p];
  float hr = ghr[p], hz = ghr[128 + p], hn = ghr[256 + p];
  float r = 1.f / (1.f + expf(-(xr + hr)));
  float z = 1.f / (1.f + expf(-(xz + hz)));
  float n = tanhf(xn + r * hn);
  hout[i] = (1.f - z) * n + z * hprev[i];
}

// ---------------------------------------------------------------------------
// Router: softmax -> top-2 (stable) -> renorm -> per-expert lists
// ---------------------------------------------------------------------------
__global__ void router_topk(const float* __restrict__ h, const float* __restrict__ Wr,
                            const float* __restrict__ br,
                            float* __restrict__ wgt, int* __restrict__ tokslot,
                            int* __restrict__ cnt)
{
  int wave = threadIdx.x >> 6;
  int lane = threadIdx.x & 63;
  int t = blockIdx.x * 4 + wave;

  float logit = 0.f;
  if (lane < NE) {
    const float* hr = h + (size_t)t * PP;
    const float* wr = Wr + (size_t)lane * PP;
    float s = 0.f;
    #pragma unroll 8
    for (int p = 0; p < PP; ++p) s += hr[p] * wr[p];
    logit = s + br[lane];
  }
  float l[NE];
  #pragma unroll
  for (int e = 0; e < NE; ++e) l[e] = __shfl(logit, e, 64);

  if (lane == 0) {
    float mx = l[0];
    #pragma unroll
    for (int e = 1; e < NE; ++e) mx = fmaxf(mx, l[e]);
    float p[NE];
    #pragma unroll
    for (int e = 0; e < NE; ++e) p[e] = expf(l[e] - mx);
    int i0 = 0; float m0 = p[0];
    #pragma unroll
    for (int e = 1; e < NE; ++e) { if (p[e] > m0) { m0 = p[e]; i0 = e; } }
    int i1 = -1; float m1 = -1.f;
    #pragma unroll
    for (int e = 0; e < NE; ++e) { if (e != i0 && p[e] > m1) { m1 = p[e]; i1 = e; } }
    float inv = 1.f / (m0 + m1);
    int pos0 = atomicAdd(&cnt[i0], 1);
    tokslot[(size_t)i0 * T_TOK + pos0] = (t << 1);
    wgt[(size_t)i0 * T_TOK + pos0] = m0 * inv;
    int pos1 = atomicAdd(&cnt[i1], 1);
    tokslot[(size_t)i1 * T_TOK + pos1] = (t << 1) | 1;
    wgt[(size_t)i1 * T_TOK + pos1] = m1 * inv;
  }
}

__global__ void zero_cnt(int* cnt) { if (threadIdx.x < NE) cnt[threadIdx.x] = 0; }

__global__ void calc_off(const int* __restrict__ cnt, int* __restrict__ offPad) {
  if (threadIdx.x == 0) {
    int s = 0;
    for (int e = 0; e < NE; ++e) { offPad[e] = s; s += (cnt[e] + 127) & ~127; }
    offPad[NE] = s;
  }
}

// ---------------------------------------------------------------------------
// Transpose+convert: in [E][K][N] f32 -> out [E][N][K] bf16  (64x64 tiles)
// ---------------------------------------------------------------------------
__global__ __launch_bounds__(256) void transpose_cvt(
    const float* __restrict__ in, unsigned short* __restrict__ out, int K, int N)
{
  __shared__ float tl[64][65];
  int e = blockIdx.z, kt = blockIdx.y, nt = blockIdx.x;
  const float* ib = in + (size_t)e * K * N + (size_t)(kt * 64) * N + nt * 64;
  int t = threadIdx.x;
  int r = t >> 2, c0 = (t & 3) * 16;
  #pragma unroll
  for (int i = 0; i < 4; ++i) {
    float4 v = *(const float4*)(ib + (size_t)r * N + c0 + i * 4);
    tl[r][c0+i*4+0] = v.x; tl[r][c0+i*4+1] = v.y;
    tl[r][c0+i*4+2] = v.z; tl[r][c0+i*4+3] = v.w;
  }
  __syncthreads();
  unsigned short* ob = out + (size_t)e * N * K + (size_t)(nt * 64) * K + kt * 64;
  #pragma unroll
  for (int i = 0; i < 2; ++i) {
    int u = t + i * 256;
    int n = u >> 3, k0 = (u & 7) * 8;
    us8 o;
    #pragma unroll
    for (int j = 0; j < 8; ++j) o[j] = f2bf(tl[k0 + j][n]);
    *(us8*)(ob + (size_t)n * K + k0) = o;
  }
}

// ---------------------------------------------------------------------------
// Gather routed tokens -> compact padded bf16 xg [rows][DM]
// ---------------------------------------------------------------------------
__global__ __launch_bounds__(256) void gather_x(
    const float* __restrict__ x, const int* __restrict__ tokslot,
    const int* __restrict__ cnt, const int* __restrict__ offPad,
    unsigned short* __restrict__ xg)
{
  int e = blockIdx.y;
  int n = cnt[e];
  int npad = (n + 127) & ~127;
  int r0 = blockIdx.x * 128;
  if (r0 >= npad) return;
  int t = threadIdx.x;
  int r = r0 + (t >> 1);
  int half = t & 1;
  unsigned short* orow = xg + (size_t)(offPad[e] + r) * DM + half * 256;
  if (r >= n) {
    us8 z = {0,0,0,0,0,0,0,0};
    #pragma unroll
    for (int i = 0; i < 32; ++i) *(us8*)(orow + i * 8) = z;
    return;
  }
  int tok = tokslot[(size_t)e * T_TOK + r] >> 1;
  const float* irow = x + (size_t)tok * DM + half * 256;
  #pragma unroll
  for (int i = 0; i < 32; ++i) {
    float4 a = *(const float4*)(irow + i * 8);
    float4 b = *(const float4*)(irow + i * 8 + 4);
    us8 o;
    o[0]=f2bf(a.x); o[1]=f2bf(a.y); o[2]=f2bf(a.z); o[3]=f2bf(a.w);
    o[4]=f2bf(b.x); o[5]=f2bf(b.y); o[6]=f2bf(b.z); o[7]=f2bf(b.w);
    *(us8*)(orow + i * 8) = o;
  }
}

// ---------------------------------------------------------------------------
// GEMM1: hidden[rows][DFF] = relu(xg[rows][DM] @ W1t^T + b1)   (bf16 MFMA)
// block: 512 thr (8 waves), tile M=128 tokens x N=256 ff, K=DM in chunks of 64
// ---------------------------------------------------------------------------
__global__ __launch_bounds__(512) void expert_gemm1(
    const unsigned short* __restrict__ xg, const unsigned short* __restrict__ W1t,
    const float* __restrict__ b1,
    const int* __restrict__ cnt, const int* __restrict__ offPad,
    unsigned short* __restrict__ hidden)
{
  int e = blockIdx.y;
  int npad = (cnt[e] + 127) & ~127;
  int tile = blockIdx.x;
  if (tile * 128 >= npad) return;
  int nb = blockIdx.z * 256;

  __shared__ unsigned short xs[128 * 64];
  __shared__ unsigned short ws1[256 * 64];

  int t = threadIdx.x;
  int lane = t & 63;
  int wv = t >> 6;
  int mg = (wv & 1) * 64;
  int ng = (wv >> 1) * 64;

  int base = offPad[e] + tile * 128;
  const unsigned short* xgb = xg + (size_t)base * DM;
  const unsigned short* w1b = W1t + ((size_t)e * DFF + nb) * DM;

  f32x4 acc[4][4];
  #pragma unroll
  for (int i = 0; i < 4; ++i)
    #pragma unroll
    for (int j = 0; j < 4; ++j) acc[i][j] = (f32x4){0.f, 0.f, 0.f, 0.f};

  for (int kc = 0; kc < DM; kc += 64) {
    #pragma unroll
    for (int i = 0; i < 2; ++i) {           // xs: 1024 16B slots
      int s = t + i * 512;
      int r = s >> 3, c = s & 7;
      GLOAD_LDS16(xgb + (size_t)r * DM + kc + ((c ^ (r & 7)) << 3), &xs[s * 8]);
    }
    #pragma unroll
    for (int i = 0; i < 4; ++i) {           // ws1: 2048 slots
      int s = t + i * 512;
      int r = s >> 3, c = s & 7;
      GLOAD_LDS16(w1b + (size_t)r * DM + kc + ((c ^ (r & 7)) << 3), &ws1[s * 8]);
    }
    __syncthreads();
    int l15 = lane & 15, lg = lane >> 4;
    #pragma unroll
    for (int kk = 0; kk < 2; ++kk) {
      int cidx = kk * 4 + lg;
      bfrag a[4], b[4];
      #pragma unroll
      for (int fi = 0; fi < 4; ++fi) {
        int row = mg + fi * 16 + l15;
        a[fi] = *(const bfrag*)&xs[row * 64 + ((cidx ^ (row & 7)) << 3)];
      }
      #pragma unroll
      for (int fj = 0; fj < 4; ++fj) {
        int row = ng + fj * 16 + l15;
        b[fj] = *(const bfrag*)&ws1[row * 64 + ((cidx ^ (row & 7)) << 3)];
      }
      #pragma unroll
      for (int fi = 0; fi < 4; ++fi)
        #pragma unroll
        for (int fj = 0; fj < 4; ++fj)
          acc[fi][fj] = __builtin_amdgcn_mfma_f32_16x16x32_bf16(a[fi], b[fj], acc[fi][fj], 0, 0, 0);
    }
    __syncthreads();
  }

  int l15 = lane & 15, lg = lane >> 4;
  unsigned short* hb = hidden + (size_t)base * DFF;
  #pragma unroll
  for (int fj = 0; fj < 4; ++fj) {
    int col = nb + ng + fj * 16 + l15;
    float bias = b1[(size_t)e * DFF + col];
    #pragma unroll
    for (int fi = 0; fi < 4; ++fi) {
      #pragma unroll
      for (int rg = 0; rg < 4; ++rg) {
        int mrow = mg + fi * 16 + lg * 4 + rg;
        float v = acc[fi][fj][rg] + bias;
        v = v > 0.f ? v : 0.f;
        hb[(size_t)mrow * DFF + col] = f2bf(v);
      }
    }
  }
}

// ---------------------------------------------------------------------------
// GEMM2: y = hidden @ W2t^T + b2, scaled scatter to pA/pB   (bf16 MFMA)
// block: 512 thr (8 waves), tile M=128 tokens x N=128 dm, K=DFF chunks of 64
// ---------------------------------------------------------------------------
__global__ __launch_bounds__(512) void expert_gemm2(
    const unsigned short* __restrict__ hidden, const unsigned short* __restrict__ W2t,
    const float* __restrict__ b2,
    const int* __restrict__ cnt, const int* __restrict__ offPad,
    const int* __restrict__ tokslot, const float* __restrict__ wgt,
    float* __restrict__ pA, float* __restrict__ pB)
{
  int e = blockIdx.y;
  int n = cnt[e];
  int npad = (n + 127) & ~127;
  int tile = blockIdx.x;
  if (tile * 128 >= npad) return;
  int nb = blockIdx.z * 128;

  __shared__ unsigned short hs[128 * 64];
  __shared__ unsigned short ws2[128 * 64];
  __shared__ int   ltok[128];
  __shared__ float lw[128];

  int t = threadIdx.x;
  if (t < 128) {
    int idx = tile * 128 + t;
    if (idx < n) {
      ltok[t] = tokslot[(size_t)e * T_TOK + idx];
      lw[t]   = wgt[(size_t)e * T_TOK + idx];
    } else { ltok[t] = -1; lw[t] = 0.f; }
  }

  int lane = t & 63;
  int wv = t >> 6;
  int mg = (wv & 1) * 64;
  int ng = (wv >> 1) * 32;

  int base = offPad[e] + tile * 128;
  const unsigned short* hbb = hidden + (size_t)base * DFF;
  const unsigned short* w2b = W2t + ((size_t)e * DM + nb) * DFF;

  f32x4 acc[4][2];
  #pragma unroll
  for (int i = 0; i < 4; ++i)
    #pragma unroll
    for (int j = 0; j < 2; ++j) acc[i][j] = (f32x4){0.f, 0.f, 0.f, 0.f};

  for (int kc = 0; kc < DFF; kc += 64) {
    #pragma unroll
    for (int i = 0; i < 2; ++i) {           // hs: 1024 slots
      int s = t + i * 512;
      int r = s >> 3, c = s & 7;
      GLOAD_LDS16(hbb + (size_t)r * DFF + kc + ((c ^ (r & 7)) << 3), &hs[s * 8]);
    }
    #pragma unroll
    for (int i = 0; i < 2; ++i) {           // ws2: 1024 slots
      int s = t + i * 512;
      int r = s >> 3, c = s & 7;
      GLOAD_LDS16(w2b + (size_t)r * DFF + kc + ((c ^ (r & 7)) << 3), &ws2[s * 8]);
    }
    __syncthreads();
    int l15 = lane & 15, lg = lane >> 4;
    #pragma unroll
    for (int kk = 0; kk < 2; ++kk) {
      int cidx = kk * 4 + lg;
      bfrag a[4], b[2];
      #pragma unroll
      for (int fi = 0; fi < 4; ++fi) {
        int row = mg + fi * 16 + l15;
        a[fi] = *(const bfrag*)&hs[row * 64 + ((cidx ^ (row & 7)) << 3)];
      }
      #pragma unroll
      for (int fj = 0; fj < 2; ++fj) {
        int row = ng + fj * 16 + l15;
        b[fj] = *(const bfrag*)&ws2[row * 64 + ((cidx ^ (row & 7)) << 3)];
      }
      #pragma unroll
      for (int fi = 0; fi < 4; ++fi)
        #pragma unroll
        for (int fj = 0; fj < 2; ++fj)
          acc[fi][fj] = __builtin_amdgcn_mfma_f32_16x16x32_bf16(a[fi], b[fj], acc[fi][fj], 0, 0, 0);
    }
    __syncthreads();
  }

  int l15 = lane & 15, lg = lane >> 4;
  #pragma unroll
  for (int fj = 0; fj < 2; ++fj) {
    int col = nb + ng + fj * 16 + l15;
    float bias = b2[(size_t)e * DM + col];
    #pragma unroll
    for (int fi = 0; fi < 4; ++fi) {
      #pragma unroll
      for (int rg = 0; rg < 4; ++rg) {
        int lrow = mg + fi * 16 + lg * 4 + rg;
        int ts = ltok[lrow];
        if (ts < 0) continue;
        float v = (acc[fi][fj][rg] + bias) * lw[lrow];
        float* dst = ((ts & 1) ? pB : pA) + (size_t)(ts >> 1) * DM + col;
        *dst = v;
      }
    }
  }
}

__global__ void combine_out(const float4* __restrict__ pA, const float4* __restrict__ pB,
                            float4* __restrict__ out)
{
  int i = blockIdx.x * blockDim.x + threadIdx.x;
  float4 a = pA[i], b = pB[i];
  out[i] = make_float4(a.x + b.x, a.y + b.y, a.z + b.z, a.w + b.w);
}

// ---------------------------------------------------------------------------
extern "C" void kernel_launch(void* const* d_in, const int* in_sizes, int n_in,
                              void* d_out, int out_size, void* d_ws, size_t ws_size,
                              hipStream_t stream)
{
  const float* x      = (const float*)d_in[0];
  const float* h_prev = (const float*)d_in[1];
  const float* Wp     = (const float*)d_in[2];
  const float* bp     = (const float*)d_in[3];
  const float* W_ih   = (const float*)d_in[4];
  const float* W_hh   = (const float*)d_in[5];
  const float* b_ih   = (const float*)d_in[6];
  const float* b_hh   = (const float*)d_in[7];
  const float* Wr     = (const float*)d_in[8];
  const float* br     = (const float*)d_in[9];
  const float* W1     = (const float*)d_in[10];
  const float* b1     = (const float*)d_in[11];
  const float* W2     = (const float*)d_in[12];
  const float* b2     = (const float*)d_in[13];
  (void)in_sizes; (void)n_in; (void)out_size; (void)ws_size;

  float* out  = (float*)d_out;                        // [T, DM]
  float* hout = out + (size_t)T_TOK * DM;             // [T, PP]

  char* ws = (char*)d_ws;
  // region A: W1t (bf16, 33.5MB), later reused for pA/pB (f32, 16.8MB)
  unsigned short* W1t = (unsigned short*)(ws + 0);
  float* pA = (float*)(ws + 0);
  float* pB = (float*)(ws + 8388608);
  // region B: W2t bf16
  unsigned short* W2t = (unsigned short*)(ws + 33554432);
  // region C: hidden bf16 (41.9MB); routing temporaries overlap (dead by then)
  unsigned short* hidden = (unsigned short*)(ws + 67108864);
  float* xp = (float*)(ws + 67108864);                // [T,PP]   2MB
  float* gx = (float*)(ws + 69206016);                // [T,3P]   6MB
  float* gh = (float*)(ws + 75497472);                // [T,3P]   6MB
  // region D: xg bf16 (10.5MB)
  unsigned short* xg = (unsigned short*)(ws + 108986368);
  // region E: router lists
  float* wgt   = (float*)(ws + 119455744);            // [E,T]
  int* tokslot = (int*)(ws + 119717888);              // [E,T]
  int* cnt     = (int*)(ws + 119980032);              // [E]
  int* offPad  = (int*)(ws + 119980096);              // [E+1]

  zero_cnt<<<1, 64, 0, stream>>>(cnt);

  // weight transpose+convert: W1 [E][512][2048] -> W1t [E][2048][512]
  transpose_cvt<<<dim3(DFF/64, DM/64, NE), 256, 0, stream>>>(W1, W1t, DM, DFF);
  // W2 [E][2048][512] -> W2t [E][512][2048]
  transpose_cvt<<<dim3(DM/64, DFF/64, NE), 256, 0, stream>>>(W2, W2t, DFF, DM);

  // routing chain (f32 for exact top-k behavior)
  sgemm_nt_bias<<<dim3(T_TOK/64, PP/64), 256, 0, stream>>>(x, Wp, bp, xp, T_TOK, PP, DM);
  sgemm_nt_bias<<<dim3(T_TOK/64, 384/64), 256, 0, stream>>>(xp, W_ih, b_ih, gx, T_TOK, 384, PP);
  sgemm_nt_bias<<<dim3(T_TOK/64, 384/64), 256, 0, stream>>>(h_prev, W_hh, b_hh, gh, T_TOK, 384, PP);
  gru_elem<<<(T_TOK * PP) / 256, 256, 0, stream>>>(gx, gh, h_prev, hout);
  router_topk<<<T_TOK / 4, 256, 0, stream>>>(hout, Wr, br, wgt, tokslot, cnt);
  calc_off<<<1, 64, 0, stream>>>(cnt, offPad);

  // expert path (bf16 MFMA)
  gather_x<<<dim3(32, NE), 256, 0, stream>>>(x, tokslot, cnt, offPad, xg);
  expert_gemm1<<<dim3(32, NE, DFF/256), 512, 0, stream>>>(xg, W1t, b1, cnt, offPad, hidden);
  expert_gemm2<<<dim3(32, NE, DM/128), 512, 0, stream>>>(hidden, W2t, b2, cnt, offPad,
                                                         tokslot, wgt, pA, pB);
  combine_out<<<(T_TOK * DM / 4) / 256, 256, 0, stream>>>((const float4*)pA, (const float4*)pB,
                                                          (float4*)out);
}